// Round 1
// baseline (15.696 us; speedup 1.0000x reference)
//
#include <hip/hip_runtime.h>
#include <hip/hip_bf16.h>

// Embedding gather: out[t, :] = embeddings[x[t], :]
// x: int32 [4*2048 = 8192], embeddings: fp32 [32000, 1024], out: fp32 [8192, 1024]
// One block per token row; 256 threads each move one float4 (16B) -> 1024 floats/row.

#define EMBED_DIM 1024
#define VEC4_PER_ROW (EMBED_DIM / 4)   // 256

__global__ __launch_bounds__(256) void embedding_gather_kernel(
    const int* __restrict__ x,
    const float4* __restrict__ emb,   // [vocab, 256] as float4
    float4* __restrict__ out,         // [ntok, 256] as float4
    int ntok)
{
    int row = blockIdx.x;
    if (row >= ntok) return;
    int col = threadIdx.x;            // 0..255, one float4 each
    int idx = x[row];                 // broadcast load (same addr all lanes -> scalar)
    out[(size_t)row * VEC4_PER_ROW + col] = emb[(size_t)idx * VEC4_PER_ROW + col];
}

extern "C" void kernel_launch(void* const* d_in, const int* in_sizes, int n_in,
                              void* d_out, int out_size, void* d_ws, size_t ws_size,
                              hipStream_t stream) {
    const int* x = (const int*)d_in[0];
    const float4* emb = (const float4*)d_in[1];
    float4* out = (float4*)d_out;

    int ntok = in_sizes[0];           // 8192
    dim3 grid(ntok);
    dim3 block(256);
    embedding_gather_kernel<<<grid, block, 0, stream>>>(x, emb, out, ntok);
}

// Round 3
// 14.639 us; speedup vs baseline: 1.0723x; 1.0723x over previous
//
#include <hip/hip_runtime.h>
#include <hip/hip_bf16.h>

// Embedding gather: out[t, :] = embeddings[x[t], :]
// x: int32 [8192], embeddings: fp32 [32000, 1024], out: fp32 [8192, 1024]
// 4 rows per block, 256 threads: each thread moves one 16B vector per row,
// all 4 gather loads issued back-to-back for memory-level parallelism.
// Native clang vector type so __builtin_nontemporal_store accepts it.

typedef float fx4 __attribute__((ext_vector_type(4)));

#define EMBED_DIM 1024
#define VEC4_PER_ROW (EMBED_DIM / 4)   // 256
#define ROWS_PER_BLOCK 4

__global__ __launch_bounds__(256) void embedding_gather_kernel(
    const int* __restrict__ x,
    const fx4* __restrict__ emb,      // [vocab, 256] as fx4
    fx4* __restrict__ out,            // [ntok, 256] as fx4
    int ntok)
{
    int base = blockIdx.x * ROWS_PER_BLOCK;
    int col = threadIdx.x;            // 0..255, one 16B vector each

    int idx[ROWS_PER_BLOCK];
#pragma unroll
    for (int i = 0; i < ROWS_PER_BLOCK; ++i) {
        int r = base + i;
        idx[i] = (r < ntok) ? x[r] : 0;   // broadcast scalar loads
    }

    fx4 v[ROWS_PER_BLOCK];
#pragma unroll
    for (int i = 0; i < ROWS_PER_BLOCK; ++i) {
        v[i] = emb[(size_t)idx[i] * VEC4_PER_ROW + col];   // 4 loads in flight
    }

#pragma unroll
    for (int i = 0; i < ROWS_PER_BLOCK; ++i) {
        int r = base + i;
        if (r < ntok) {
            // non-temporal: don't let the 33 MB output evict the L3-resident table
            __builtin_nontemporal_store(v[i], &out[(size_t)r * VEC4_PER_ROW + col]);
        }
    }
}

extern "C" void kernel_launch(void* const* d_in, const int* in_sizes, int n_in,
                              void* d_out, int out_size, void* d_ws, size_t ws_size,
                              hipStream_t stream) {
    const int* x = (const int*)d_in[0];
    const fx4* emb = (const fx4*)d_in[1];
    fx4* out = (fx4*)d_out;

    int ntok = in_sizes[0];           // 8192
    int nblocks = (ntok + ROWS_PER_BLOCK - 1) / ROWS_PER_BLOCK;   // 2048
    embedding_gather_kernel<<<dim3(nblocks), dim3(256), 0, stream>>>(x, emb, out, ntok);
}